// Round 1
// 858.953 us; speedup vs baseline: 1.0037x; 1.0037x over previous
//
#include <hip/hip_runtime.h>
#include <math.h>

// Problem: B=8192, C=128.
// mu_out = softmax(mu_in); Sigma_out = J Sigma J^T, J = diag(p) - p p^T.
// Closed form: Sigma_out[i][l] = p_i * p_l * (Sigma[i][l] - r_i - s_l + q)
//   r = Sigma p, s = p^T Sigma, q = p^T Sigma p.
// Memory-bound: 512 MiB read + 512 MiB write of Sigma -> ~170 us floor @6.3TB/s.
//
// This version keeps the whole Sigma tile IN REGISTERS (no 64KB LDS staging):
//   flat index f = t + 256*it  ->  row = (t>>5) + 8*it, cols [4*(t&31), +4).
//   r: 32-lane shfl_xor reduction (a row lives in 32 consecutive lanes).
//   s: per-thread accumulation over its 16 rows + 8-way cross-group LDS sum (4KB).
//   q: by-product of the r partials, one block reduction.
// LDS 67KB -> ~5.6KB, so occupancy goes 2 -> 4 blocks/CU (launch_bounds(256,4)).

#define C 128
#define BLOCK 256

__device__ __forceinline__ float reduce32_sum(float v) {
    #pragma unroll
    for (int off = 16; off > 0; off >>= 1) v += __shfl_xor(v, off, 64);
    return v;
}
__device__ __forceinline__ float wave_reduce_sum(float v) {
    #pragma unroll
    for (int off = 32; off > 0; off >>= 1) v += __shfl_xor(v, off, 64);
    return v;
}
__device__ __forceinline__ float wave_reduce_max(float v) {
    #pragma unroll
    for (int off = 32; off > 0; off >>= 1) v = fmaxf(v, __shfl_xor(v, off, 64));
    return v;
}

__global__ __launch_bounds__(BLOCK, 4) void jsj_kernel(
    const float* __restrict__ mu_in,
    const float* __restrict__ Sigma_in,
    float* __restrict__ mu_out,
    float* __restrict__ Sigma_out)
{
    const int b    = blockIdx.x;
    const int t    = threadIdx.x;
    const int wave = t >> 6;
    const int lane = t & 63;
    const int g    = t >> 5;      // row-group 0..7 (32 consecutive lanes)
    const int cq   = t & 31;      // column-quad; this thread owns cols [4cq, 4cq+4)

    __shared__ float  p[C];
    __shared__ float  rs[C];
    __shared__ float  red[8];
    __shared__ float4 sp[8][32];  // per-row-group column partial sums (4 KB)

    // ---- issue the Sigma tile loads first (16 x float4 per thread, coalesced)
    const float4* Sg = (const float4*)(Sigma_in + (size_t)b * (C * C));
    float4 v[16];
    #pragma unroll
    for (int it = 0; it < 16; ++it)
        v[it] = Sg[t + it * BLOCK];

    // ---- softmax over mu row while the global loads are in flight
    float x = (t < C) ? mu_in[b * C + t] : -INFINITY;
    float m = wave_reduce_max(x);
    if (lane == 0) red[wave] = m;
    __syncthreads();
    m = fmaxf(fmaxf(red[0], red[1]), fmaxf(red[2], red[3]));
    float e = (t < C) ? expf(x - m) : 0.0f;
    float es = wave_reduce_sum(e);
    if (lane == 0) red[4 + wave] = es;   // disjoint slots from red[0..3]
    __syncthreads();
    float denom = red[4] + red[5] + red[6] + red[7];
    float pt = e / denom;
    if (t < C) { p[t] = pt; mu_out[b * C + t] = pt; }
    __syncthreads();

    // ---- this thread's p fragment (cols) — 16B-aligned LDS vector read
    const float4 p4 = *(const float4*)&p[cq * 4];

    // ---- r (row dots), s (column sums), q — all from registers
    float4 s4 = make_float4(0.f, 0.f, 0.f, 0.f);
    float qpart = 0.0f;
    #pragma unroll
    for (int it = 0; it < 16; ++it) {
        const int row  = g + 8 * it;
        const float pr = p[row];                       // broadcast read
        float part = v[it].x * p4.x + v[it].y * p4.y
                   + v[it].z * p4.z + v[it].w * p4.w;  // partial row-dot
        qpart += pr * part;                            // sums to q over the block
        s4.x  += pr * v[it].x;
        s4.y  += pr * v[it].y;
        s4.z  += pr * v[it].z;
        s4.w  += pr * v[it].w;
        float r = reduce32_sum(part);                  // full r_row in 32-lane group
        if (cq == 0) rs[row] = r;                      // 8 leaders x 16 rows = 128
    }
    sp[g][cq] = s4;                                    // byte addr = t*16: linear
    qpart = wave_reduce_sum(qpart);
    if (lane == 0) red[wave] = qpart;
    __syncthreads();

    const float q = red[0] + red[1] + red[2] + red[3];
    float4 ss4 = sp[0][cq];
    #pragma unroll
    for (int gg = 1; gg < 8; ++gg) {
        float4 w = sp[gg][cq];
        ss4.x += w.x; ss4.y += w.y; ss4.z += w.z; ss4.w += w.w;
    }

    // ---- epilogue: Sigma_out[i][l] = p_i p_l (S[i][l] - ss[l] - rs[i] + q)
    float4* Og = (float4*)(Sigma_out + (size_t)b * (C * C));
    #pragma unroll
    for (int it = 0; it < 16; ++it) {
        const int row   = g + 8 * it;
        const float pi  = p[row];                      // broadcast
        const float base = q - rs[row];                // broadcast
        float4 o;
        o.x = pi * p4.x * (v[it].x - ss4.x + base);
        o.y = pi * p4.y * (v[it].y - ss4.y + base);
        o.z = pi * p4.z * (v[it].z - ss4.z + base);
        o.w = pi * p4.w * (v[it].w - ss4.w + base);
        Og[t + it * BLOCK] = o;
    }
}

extern "C" void kernel_launch(void* const* d_in, const int* in_sizes, int n_in,
                              void* d_out, int out_size, void* d_ws, size_t ws_size,
                              hipStream_t stream) {
    const float* mu_in    = (const float*)d_in[0];
    const float* Sigma_in = (const float*)d_in[1];
    const int B = in_sizes[0] / C;          // 8192

    float* mu_out    = (float*)d_out;                  // B*C floats
    float* Sigma_out = (float*)d_out + (size_t)B * C;  // B*C*C floats

    jsj_kernel<<<B, BLOCK, 0, stream>>>(mu_in, Sigma_in, mu_out, Sigma_out);
}